// Round 7
// baseline (195.278 us; speedup 1.0000x reference)
//
#include <hip/hip_runtime.h>
#include <math.h>

// Problem constants (fixed by the reference):
#define B_  4
#define C_  256     // in/out channels
#define CI_ 128     // inter channels (attention head dim D)
#define N_  4096    // H*W

typedef short s16x8  __attribute__((ext_vector_type(8)));    // 8 bf16 (4 VGPRs)
typedef float f32x4  __attribute__((ext_vector_type(4)));    // 16x16 accumulator
typedef float f32x16 __attribute__((ext_vector_type(16)));   // 32x32 accumulator

// fp32 -> bf16 (RNE)
__device__ inline ushort f2bf(float f) {
    unsigned int u = __float_as_uint(f);
    u += 0x7FFF + ((u >> 16) & 1);
    return (ushort)(u >> 16);
}
__device__ inline float bf2f(ushort u) {
    return __uint_as_float(((unsigned int)u) << 16);
}

// LDS-only workgroup sync (no vmcnt drain; prefetch loads stay in flight).
__device__ inline void block_sync_lds() {
    asm volatile("s_waitcnt lgkmcnt(0)" ::: "memory");
    __builtin_amdgcn_s_barrier();
    asm volatile("" ::: "memory");
}
// Intra-wave LDS write->read ordering only.
__device__ inline void wave_lds_fence() {
    asm volatile("s_waitcnt lgkmcnt(0)" ::: "memory");
}

// ---------------------------------------------------------------------------
// Weight cast: Wcat = [Wg;Wt;Wp] bf16 (384x256), Wobf bf16 (256x128),
// bcat = [bg;bt;bp] fp32 (384). Grid 512x256.
// ---------------------------------------------------------------------------
__global__ __launch_bounds__(256) void wcast_kernel(
    const float* __restrict__ Wg, const float* __restrict__ Wt,
    const float* __restrict__ Wp, const float* __restrict__ Wo,
    const float* __restrict__ bg, const float* __restrict__ bt,
    const float* __restrict__ bp,
    ushort* __restrict__ Wcat, ushort* __restrict__ Wobf,
    float* __restrict__ bcat)
{
    int i = blockIdx.x * 256 + threadIdx.x;
    if (i < 32768)       Wcat[i] = f2bf(Wg[i]);
    else if (i < 65536)  Wcat[i] = f2bf(Wt[i - 32768]);
    else if (i < 98304)  Wcat[i] = f2bf(Wp[i - 65536]);
    else if (i < 131072) Wobf[i - 98304] = f2bf(Wo[i - 98304]);
    if (i < 128)         bcat[i] = bg[i];
    else if (i < 256)    bcat[i] = bt[i - 128];
    else if (i < 384)    bcat[i] = bp[i - 256];
}

// ---------------------------------------------------------------------------
// x transpose+cast: x [B][C][N] fp32 -> xT [B][N][C] bf16. Tile 64c x 64n.
// ---------------------------------------------------------------------------
__global__ __launch_bounds__(256) void xt_kernel(
    const float* __restrict__ x, ushort* __restrict__ xT)
{
    __shared__ ushort Ls[64][72];
    const int b = blockIdx.z, c0 = blockIdx.y * 64, n0 = blockIdx.x * 64;
    const float* xb = x + ((size_t)b * C_ + c0) * N_ + n0;
    const int t = threadIdx.x;
    #pragma unroll
    for (int r = 0; r < 4; r++) {
        int idx = t + 256 * r;
        int c = idx >> 4, n4 = (idx & 15) * 4;
        float4 v = *(const float4*)&xb[(size_t)c * N_ + n4];
        ushort4 o;
        o.x = f2bf(v.x); o.y = f2bf(v.y); o.z = f2bf(v.z); o.w = f2bf(v.w);
        *(ushort4*)&Ls[c][n4] = o;
    }
    __syncthreads();
    ushort* xTb = xT + ((size_t)b * N_ + n0) * C_ + c0;
    #pragma unroll
    for (int r = 0; r < 2; r++) {
        int idx = t + 256 * r;
        int n = idx >> 3, c8 = (idx & 7) * 8;
        ushort tmp[8];
        #pragma unroll
        for (int u = 0; u < 8; u++) tmp[u] = Ls[c8 + u][n];
        *(uint4*)&xTb[(size_t)n * C_ + c8] = *(uint4*)tmp;
    }
}

// ---------------------------------------------------------------------------
// Fused projection GEMM (bf16 MFMA, 16x16x32). Grid (N/64, 6, B).
// ---------------------------------------------------------------------------
__global__ __launch_bounds__(256) void proj_kernel(
    const ushort* __restrict__ Wcat, const float* __restrict__ bcat,
    const ushort* __restrict__ xT,
    ushort* __restrict__ g, ushort* __restrict__ tht, ushort* __restrict__ pht)
{
    __shared__ ushort Ws[64][72];
    __shared__ ushort Xs[64][72];
    const int b = blockIdx.z, mt = blockIdx.y, n0 = blockIdx.x * 64;
    const int t = threadIdx.x, wv = t >> 6, lane = t & 63;
    const int g4 = lane >> 4, ln = lane & 15;
    const ushort* Wsrc = Wcat + (size_t)mt * 64 * C_;
    const ushort* Xsrc = xT + ((size_t)b * N_ + n0) * C_;

    f32x4 acc[4];
    #pragma unroll
    for (int i = 0; i < 4; i++) acc[i] = (f32x4){0.f, 0.f, 0.f, 0.f};

    for (int k0 = 0; k0 < C_; k0 += 64) {
        block_sync_lds();
        #pragma unroll
        for (int r = 0; r < 2; r++) {
            int idx = t + 256 * r;
            int row = idx >> 3, k8 = (idx & 7) * 8;
            *(uint4*)&Ws[row][k8] = *(const uint4*)&Wsrc[(size_t)row * C_ + k0 + k8];
            *(uint4*)&Xs[row][k8] = *(const uint4*)&Xsrc[(size_t)row * C_ + k0 + k8];
        }
        block_sync_lds();
        if (mt < 2) {
            #pragma unroll
            for (int kk = 0; kk < 2; kk++) {
                s16x8 aW = *(const s16x8*)&Ws[16 * wv + ln][32 * kk + 8 * g4];
                #pragma unroll
                for (int nt = 0; nt < 4; nt++) {
                    s16x8 bX = *(const s16x8*)&Xs[16 * nt + ln][32 * kk + 8 * g4];
                    acc[nt] = __builtin_amdgcn_mfma_f32_16x16x32_bf16(aW, bX, acc[nt], 0, 0, 0);
                }
            }
        } else {
            #pragma unroll
            for (int kk = 0; kk < 2; kk++) {
                s16x8 aX = *(const s16x8*)&Xs[16 * wv + ln][32 * kk + 8 * g4];
                #pragma unroll
                for (int ct = 0; ct < 4; ct++) {
                    s16x8 bW = *(const s16x8*)&Ws[16 * ct + ln][32 * kk + 8 * g4];
                    acc[ct] = __builtin_amdgcn_mfma_f32_16x16x32_bf16(aX, bW, acc[ct], 0, 0, 0);
                }
            }
        }
    }

    if (mt < 2) {
        ushort* ob = g + (size_t)b * CI_ * N_;
        #pragma unroll
        for (int r = 0; r < 4; r++) {
            int mloc = 16 * wv + 4 * g4 + r;
            float bi = bcat[mt * 64 + mloc];
            #pragma unroll
            for (int nt = 0; nt < 4; nt++)
                ob[(size_t)(mt * 64 + mloc) * N_ + n0 + 16 * nt + ln] = f2bf(acc[nt][r] + bi);
        }
    } else {
        ushort* ob = ((mt < 4) ? tht : pht) + (size_t)b * N_ * CI_;
        int cib = ((mt - 2) & 1) * 64;
        #pragma unroll
        for (int r = 0; r < 4; r++) {
            int nloc = 16 * wv + 4 * g4 + r;
            #pragma unroll
            for (int ct = 0; ct < 4; ct++) {
                float bi = bcat[mt * 64 + 16 * ct + ln];
                ob[(size_t)(n0 + nloc) * CI_ + cib + 16 * ct + ln] = f2bf(acc[ct][r] + bi);
            }
        }
    }
}

// ---------------------------------------------------------------------------
// MFMA flash attention, S^T formulation (32x32x16).
//   S^T = mfma(A=K-rows, B=Q-rows)  -> lane owns a q-COLUMN of scores.
//   P^T stays in registers; A<->B transform = exchange 4 packed b32 with
//   lane^32 (__shfl_xor) per k-step. O^T = mfma(A=V^T-rows, B=P^T).
//   l = per-lane register sum of exp values (+1 shfl at end). No P LDS
//   round-trip, no ones-MFMA, no Q staging (aQ direct from global).
// LDS: Ks[64][136] + Vt[128][72] = 35840 B. Q-tile 128, J-tile 64, 4 chunks.
// Layouts (HW-validated by round-5 pass):
//   A: lane holds A[m=lane&31][k=8*(lane>>5)+e]
//   B: lane holds B[k=8*(lane>>5)+e][n=lane&31]
//   C/D: col=lane&31, row=(reg&3)+8*(reg>>2)+4*(lane>>5)
// ---------------------------------------------------------------------------
#define SQK 136   // K row stride (bf16), 272 B
#define SPV 72    // V^T row stride (bf16), 144 B
#define JCHUNK 1024

__global__ __launch_bounds__(256, 2) void attn_mfma_kernel(
    const ushort* __restrict__ qn,   // [B][N][CI]
    const ushort* __restrict__ kn,   // [B][N][CI]
    const ushort* __restrict__ vm,   // [B][CI][N]
    ushort* __restrict__ Opart,      // [4][B][N][CI] bf16 (unnormalized)
    float* __restrict__ lbuf)        // [4][B][N] row sums
{
    __shared__ __align__(16) ushort smem[17920];   // 35840 B
    ushort* Ks = smem;                 // [64][SQK]  = 8704 sh
    ushort* Vt = smem + 8704;          // [128][SPV] = 9216 sh
    // epilogue: per-wave [32][136] transpose buffers alias Ks (4*4352 sh)

    const int b     = blockIdx.z;
    const int chunk = blockIdx.y;
    const int i0    = blockIdx.x * 128;
    const int jbase = chunk * JCHUNK;
    const int t     = threadIdx.x;
    const int wv    = t >> 6;
    const int lane  = t & 63;
    const int n32   = lane & 31;
    const int h     = lane >> 5;

    const ushort* qb = qn + ((size_t)b * N_ + i0) * CI_;
    const ushort* kb = kn + (size_t)b * N_ * CI_;
    const ushort* vb = vm + (size_t)b * CI_ * N_;

    // ---- aQ (B-operand) direct from global: row q = i0+32wv+n32
    s16x8 aQ[8];
    {
        const ushort* qrow = qb + (size_t)(32 * wv + n32) * CI_ + 8 * h;
        #pragma unroll
        for (int kk = 0; kk < 8; kk++)
            aQ[kk] = *(const s16x8*)&qrow[16 * kk];
    }

    f32x16 Oacc[4];
    #pragma unroll
    for (int dt = 0; dt < 4; dt++)
        #pragma unroll
        for (int e = 0; e < 16; e++) Oacc[dt][e] = 0.f;
    float l_run = 0.f;

    // ---- prefetch first j-tile
    uint4 pfK[4], pfV[4];
    #pragma unroll
    for (int r = 0; r < 4; r++) {
        int idx = t + 256 * r;
        int row = idx >> 4, ch = idx & 15;
        pfK[r] = *(const uint4*)&kb[(size_t)(jbase + row) * CI_ + ch * 8];
    }
    #pragma unroll
    for (int r = 0; r < 4; r++) {
        int idx = t + 256 * r;
        int d = idx >> 3, ch = idx & 7;
        pfV[r] = *(const uint4*)&vb[(size_t)d * N_ + jbase + ch * 8];
    }

    for (int jt = jbase; jt < jbase + JCHUNK; jt += 64) {
        block_sync_lds();   // prev tile's LDS reads retired everywhere
        #pragma unroll
        for (int r = 0; r < 4; r++) {
            int idx = t + 256 * r;
            int row = idx >> 4, ch = idx & 15;
            *(uint4*)&Ks[row * SQK + ch * 8] = pfK[r];
        }
        #pragma unroll
        for (int r = 0; r < 4; r++) {
            int idx = t + 256 * r;
            int d = idx >> 3, ch = idx & 7;
            *(uint4*)&Vt[d * SPV + ch * 8] = pfV[r];
        }
        block_sync_lds();   // K/V visible

        if (jt + 64 < jbase + JCHUNK) {
            const ushort* ksrc = kb + (size_t)(jt + 64) * CI_;
            #pragma unroll
            for (int r = 0; r < 4; r++) {
                int idx = t + 256 * r;
                int row = idx >> 4, ch = idx & 15;
                pfK[r] = *(const uint4*)&ksrc[(size_t)row * CI_ + ch * 8];
            }
            #pragma unroll
            for (int r = 0; r < 4; r++) {
                int idx = t + 256 * r;
                int d = idx >> 3, ch = idx & 7;
                pfV[r] = *(const uint4*)&vb[(size_t)d * N_ + jt + 64 + ch * 8];
            }
        }

        // ---- S^T = K Q^T : 2 j-subtiles (rows), q-cols = this wave's strip
        f32x16 S0, S1;
        #pragma unroll
        for (int e = 0; e < 16; e++) { S0[e] = 0.f; S1[e] = 0.f; }
        #pragma unroll
        for (int kk = 0; kk < 8; kk++) {
            s16x8 bK0 = *(const s16x8*)&Ks[n32 * SQK + 16 * kk + 8 * h];
            s16x8 bK1 = *(const s16x8*)&Ks[(32 + n32) * SQK + 16 * kk + 8 * h];
            S0 = __builtin_amdgcn_mfma_f32_32x32x16_bf16(bK0, aQ[kk], S0, 0, 0, 0);
            S1 = __builtin_amdgcn_mfma_f32_32x32x16_bf16(bK1, aQ[kk], S1, 0, 0, 0);
        }

        // ---- P^T = exp(S^T): pack row-adjacent pairs into b32; accumulate l
        int pk[16], qk[16];
        #pragma unroll
        for (int i2 = 0; i2 < 8; i2++) {
            float lo = __expf(S0[2 * i2]), hi = __expf(S0[2 * i2 + 1]);
            l_run += lo + hi;
            pk[i2] = (int)((unsigned)f2bf(lo) | ((unsigned)f2bf(hi) << 16));
        }
        #pragma unroll
        for (int i2 = 0; i2 < 8; i2++) {
            float lo = __expf(S1[2 * i2]), hi = __expf(S1[2 * i2 + 1]);
            l_run += lo + hi;
            pk[8 + i2] = (int)((unsigned)f2bf(lo) | ((unsigned)f2bf(hi) << 16));
        }
        #pragma unroll
        for (int i2 = 0; i2 < 16; i2++)
            qk[i2] = __shfl_xor(pk[i2], 32, 64);

        // ---- O^T += V^T P^T : per subtile s, k-step tp (16 j each)
        #pragma unroll
        for (int s = 0; s < 2; s++) {
            #pragma unroll
            for (int tp = 0; tp < 2; tp++) {
                int ix = 8 * s + 4 * tp;
                union { int i[4]; s16x8 v; } u;
                if (h == 0) {
                    u.i[0] = pk[ix];     u.i[1] = pk[ix + 1];
                    u.i[2] = qk[ix];     u.i[3] = qk[ix + 1];
                } else {
                    u.i[0] = qk[ix + 2]; u.i[1] = qk[ix + 3];
                    u.i[2] = pk[ix + 2]; u.i[3] = pk[ix + 3];
                }
                #pragma unroll
                for (int dsub = 0; dsub < 4; dsub++) {
                    s16x8 aV = *(const s16x8*)&Vt[(32 * dsub + n32) * SPV + 32 * s + 16 * tp + 8 * h];
                    Oacc[dsub] = __builtin_amdgcn_mfma_f32_32x32x16_bf16(aV, u.v, Oacc[dsub], 0, 0, 0);
                }
            }
        }
    }

    // ---- epilogue: O^T regs -> per-wave LDS transpose -> coalesced [n][d]
    block_sync_lds();   // all K/V LDS reads done before reusing Ks region
    ushort* tb = smem + wv * 4352;   // [32 q][136 d-stride]
    #pragma unroll
    for (int rg = 0; rg < 16; rg++) {
        int R = (rg & 3) + 8 * (rg >> 2) + 4 * h;
        #pragma unroll
        for (int dsub = 0; dsub < 4; dsub++)
            tb[n32 * 136 + 32 * dsub + R] = f2bf(Oacc[dsub][rg]);
    }
    wave_lds_fence();   // intra-wave: tb writes -> tb reads
    ushort* Ob = Opart + (size_t)chunk * (B_ * N_ * CI_) + ((size_t)b * N_ + i0) * CI_;
    #pragma unroll
    for (int k = 0; k < 8; k++) {
        int idx = lane + 64 * k;
        int row = idx >> 4, c = idx & 15;
        uint4 val = *(const uint4*)&tb[row * 136 + c * 8];
        *(uint4*)&Ob[(size_t)(32 * wv + row) * CI_ + c * 8] = val;
    }
    float lsum = l_run + __shfl_xor(l_run, 32, 64);
    if (h == 0)
        lbuf[((size_t)chunk * B_ + b) * N_ + i0 + 32 * wv + n32] = lsum;
}

// ---------------------------------------------------------------------------
// Output GEMM (bf16 MFMA), M-tile 128 (halves Opart re-reads), fused 4-chunk
// combine in staging. Grid (N/64, C/128, B) = (64, 2, 4).
// ---------------------------------------------------------------------------
__global__ __launch_bounds__(256) void outgemm_kernel(
    const ushort* __restrict__ Wobf, const float* __restrict__ bo,
    const ushort* __restrict__ Opart, const float* __restrict__ lbuf,
    const float* __restrict__ x, float* __restrict__ out)
{
    __shared__ ushort Ws[128][72];
    __shared__ ushort Ys[64][72];
    const int b = blockIdx.z, m0 = blockIdx.y * 128, n0 = blockIdx.x * 64;
    const int t = threadIdx.x, wv = t >> 6, lane = t & 63;
    const int g4 = lane >> 4, ln = lane & 15;
    const ushort* Wsrc = Wobf + (size_t)m0 * CI_;
    const size_t cs = (size_t)B_ * N_ * CI_;   // chunk stride

    f32x4 acc[2][4];
    #pragma unroll
    for (int i = 0; i < 2; i++)
        #pragma unroll
        for (int j = 0; j < 4; j++) acc[i][j] = (f32x4){0.f, 0.f, 0.f, 0.f};

    for (int k0 = 0; k0 < CI_; k0 += 64) {
        block_sync_lds();
        #pragma unroll
        for (int r = 0; r < 4; r++) {
            int idx = t + 256 * r;
            int row = idx >> 3, k8 = (idx & 7) * 8;
            *(uint4*)&Ws[row][k8] = *(const uint4*)&Wsrc[(size_t)row * CI_ + k0 + k8];
        }
        #pragma unroll
        for (int r = 0; r < 2; r++) {
            int idx = t + 256 * r;
            int row = idx >> 3, k8 = (idx & 7) * 8;
            size_t obase = ((size_t)b * N_ + n0 + row) * CI_ + k0 + k8;
            float lsum = 0.f;
            #pragma unroll
            for (int c = 0; c < 4; c++)
                lsum += lbuf[((size_t)c * B_ + b) * N_ + n0 + row];
            float inv = 1.0f / lsum;
            ushort o0[8], o1[8], o2[8], o3[8], yo[8];
            *(uint4*)o0 = *(const uint4*)&Opart[obase];
            *(uint4*)o1 = *(const uint4*)&Opart[cs + obase];
            *(uint4*)o2 = *(const uint4*)&Opart[2 * cs + obase];
            *(uint4*)o3 = *(const uint4*)&Opart[3 * cs + obase];
            #pragma unroll
            for (int u = 0; u < 8; u++)
                yo[u] = f2bf((bf2f(o0[u]) + bf2f(o1[u]) + bf2f(o2[u]) + bf2f(o3[u])) * inv);
            *(uint4*)&Ys[row][k8] = *(uint4*)yo;
        }
        block_sync_lds();
        #pragma unroll
        for (int kk = 0; kk < 2; kk++) {
            #pragma unroll
            for (int sm = 0; sm < 2; sm++) {
                s16x8 aW = *(const s16x8*)&Ws[16 * (2 * wv + sm) + ln][32 * kk + 8 * g4];
                #pragma unroll
                for (int nt = 0; nt < 4; nt++) {
                    s16x8 bY = *(const s16x8*)&Ys[16 * nt + ln][32 * kk + 8 * g4];
                    acc[sm][nt] = __builtin_amdgcn_mfma_f32_16x16x32_bf16(aW, bY, acc[sm][nt], 0, 0, 0);
                }
            }
        }
    }

    float* outb = out + (size_t)b * C_ * N_;
    const float* xb = x + (size_t)b * C_ * N_;
    #pragma unroll
    for (int sm = 0; sm < 2; sm++) {
        #pragma unroll
        for (int r = 0; r < 4; r++) {
            int m = m0 + 16 * (2 * wv + sm) + 4 * g4 + r;
            float bi = bo[m];
            #pragma unroll
            for (int nt = 0; nt < 4; nt++) {
                size_t idx = (size_t)m * N_ + n0 + 16 * nt + ln;
                outb[idx] = acc[sm][nt][r] + bi + xb[idx];
            }
        }
    }
}

// ---------------------------------------------------------------------------
extern "C" void kernel_launch(void* const* d_in, const int* in_sizes, int n_in,
                              void* d_out, int out_size, void* d_ws, size_t ws_size,
                              hipStream_t stream) {
    const float* x  = (const float*)d_in[0];
    const float* Wg = (const float*)d_in[1];
    const float* bg = (const float*)d_in[2];
    const float* Wt = (const float*)d_in[3];
    const float* bt = (const float*)d_in[4];
    const float* Wp = (const float*)d_in[5];
    const float* bp = (const float*)d_in[6];
    const float* Wo = (const float*)d_in[7];
    const float* bo = (const float*)d_in[8];
    float* out = (float*)d_out;

    // ws layout (bytes). xT (8 MB) dead after proj; Opart (16 MB) aliases it.
    char* w = (char*)d_ws;
    ushort* xT    = (ushort*)w;                   // [B][N][C]  bf16, 8 MB
    ushort* Opart = (ushort*)w;                   // [4][B][N][CI] bf16, 16 MB
    ushort* g     = (ushort*)(w + 16777216);      // [B][CI][N] bf16, 4 MB
    ushort* tht   = (ushort*)(w + 20971520);      // [B][N][CI] bf16, 4 MB
    ushort* pht   = (ushort*)(w + 25165824);      // [B][N][CI] bf16, 4 MB
    ushort* Wcat  = (ushort*)(w + 29360128);      // [384][256] bf16
    ushort* Wobf  = (ushort*)(w + 29556736);      // [256][128] bf16
    float*  bcat  = (float*) (w + 29622272);      // [384]
    float*  lbuf  = (float*) (w + 29623808);      // [4][B][N] fp32, 256 KB

    dim3 blk(256);
    wcast_kernel<<<512, blk, 0, stream>>>(Wg, Wt, Wp, Wo, bg, bt, bp, Wcat, Wobf, bcat);
    xt_kernel<<<dim3(N_ / 64, C_ / 64, B_), blk, 0, stream>>>(x, xT);
    proj_kernel<<<dim3(N_ / 64, 6, B_), blk, 0, stream>>>(Wcat, bcat, xT, g, tht, pht);
    attn_mfma_kernel<<<dim3(N_ / 128, 4, B_), blk, 0, stream>>>(tht, pht, g, Opart, lbuf);
    outgemm_kernel<<<dim3(N_ / 64, C_ / 128, B_), blk, 0, stream>>>(Wobf, bo, Opart, lbuf, x, out);
}